// Round 1
// baseline (352.246 us; speedup 1.0000x reference)
//
#include <hip/hip_runtime.h>

// Submanifold sparse 3D conv, fp32 baseline.
// out = feats @ W[13]                          (center, identity map, plain store)
// out[omap[k,p]] += feats[imap[k,p]] @ W[k']   (26 offsets, atomicAdd)
//
// Layout facts (from reference):
//   feats  [N=200000][64] f32
//   kernel [27][Cin=64][Cout=64] f32 ; center index 13; offset k -> kernel k<13?k:k+1
//   imap/omap [26][P] i32, -1 padded at the tail of each row

#define CIN 64
#define COUT 64
#define PAIRS_PER_BLOCK 256
#define PAIRS_PER_WAVE 64

// MODE 0: center (i = j = p, store).  MODE 1: offsets (mapped, atomicAdd).
template <int MODE>
__global__ __launch_bounds__(256) void spconv_kernel(
    const float* __restrict__ feats,
    const float* __restrict__ W,      // [27][64][64]
    const int* __restrict__ imap,     // [26][P] (unused MODE 0)
    const int* __restrict__ omap,     // [26][P] (unused MODE 0)
    float* __restrict__ out,          // [N][64]
    int npairs)                        // P (MODE 1) or N (MODE 0)
{
    // W[this offset] transposed in LDS as float4: wt4[c4*64 + o] = {W[4c4..4c4+3][o]}
    __shared__ float4 wt4[16 * 64];

    const int tid = threadIdx.x;
    const int koff = blockIdx.y;

    const float* Wk;
    const int* im = nullptr;
    const int* om = nullptr;
    if (MODE == 0) {
        Wk = W + 13 * (CIN * COUT);
    } else {
        const int kk = (koff < 13) ? koff : koff + 1;
        Wk = W + (size_t)kk * (CIN * COUT);
        im = imap + (size_t)koff * npairs;
        om = omap + (size_t)koff * npairs;
    }

    // Stage W transposed into LDS (coalesced global read; 8-way LDS write
    // conflict but only 16 writes/thread once per block).
    float* wts = (float*)wt4;
    for (int idx = tid; idx < CIN * COUT; idx += 256) {
        const int c = idx >> 6;       // cin
        const int o = idx & 63;       // cout
        wts[((c >> 2) * 64 + o) * 4 + (c & 3)] = Wk[idx];
    }
    __syncthreads();

    const int o = tid & 63;           // lane = output channel
    const int w = tid >> 6;           // wave id
    const int base = blockIdx.x * PAIRS_PER_BLOCK + w * PAIRS_PER_WAVE;
    const float4* __restrict__ f4p = (const float4*)feats;

    for (int n = 0; n < PAIRS_PER_WAVE; ++n) {
        const int p = base + n;
        if (p >= npairs) break;

        int i, j;
        if (MODE == 0) {
            i = p; j = p;
        } else {
            i = im[p];
            if (i < 0) continue;      // -1 tail padding: masked pair, contributes 0
            j = om[p];
        }
        i = __builtin_amdgcn_readfirstlane(i);  // wave-uniform: scalar path

        float acc = 0.f;
#pragma unroll
        for (int c4 = 0; c4 < 16; ++c4) {
            const float4 f = f4p[(size_t)i * 16 + c4];   // wave-uniform 16B load
            const float4 wv = wt4[c4 * 64 + o];          // conflict-free b128
            acc += f.x * wv.x + f.y * wv.y + f.z * wv.z + f.w * wv.w;
        }

        if (MODE == 0) {
            out[(size_t)j * COUT + o] = acc;             // initializes every row
        } else {
            atomicAdd(&out[(size_t)j * COUT + o], acc);
        }
    }
}

extern "C" void kernel_launch(void* const* d_in, const int* in_sizes, int n_in,
                              void* d_out, int out_size, void* d_ws, size_t ws_size,
                              hipStream_t stream) {
    const float* feats = (const float*)d_in[0];
    const float* W     = (const float*)d_in[1];
    const int* imap    = (const int*)d_in[2];
    const int* omap    = (const int*)d_in[3];
    float* out         = (float*)d_out;

    const int N = in_sizes[0] / CIN;   // 200000
    const int P = in_sizes[2] / 26;    // padded pairs per offset

    // 1) Center: writes every output row (no zero-init needed, overwrites poison).
    dim3 blk(256);
    dim3 gc((N + PAIRS_PER_BLOCK - 1) / PAIRS_PER_BLOCK, 1);
    spconv_kernel<0><<<gc, blk, 0, stream>>>(feats, W, nullptr, nullptr, out, N);

    // 2) 26 offsets: gather-GEMV-scatter with atomics (stream-ordered after center).
    dim3 go((P + PAIRS_PER_BLOCK - 1) / PAIRS_PER_BLOCK, 26);
    spconv_kernel<1><<<go, blk, 0, stream>>>(feats, W, imap, omap, out, P);
}